// Round 5
// baseline (397.089 us; speedup 1.0000x reference)
//
#include <hip/hip_runtime.h>
#include <hip/hip_cooperative_groups.h>

namespace cg = cooperative_groups;

typedef unsigned short ushort_t;
typedef _Float16 f16_t;
typedef _Float16 f16x2 __attribute__((ext_vector_type(2)));
typedef short bf16x8 __attribute__((ext_vector_type(8)));
typedef float f32x4 __attribute__((ext_vector_type(4)));

#define B_ 128
#define L_ 200
#define D_ 128
#define M_ 64

// ---------- helpers ----------
__device__ __forceinline__ float fast_sigmoid(float x) {
    return 1.f / (1.f + __expf(-x));
}

__device__ __forceinline__ float fast_tanh(float x) {
    float xc = fminf(fmaxf(x, -15.f), 15.f);
    float e = __expf(2.f * xc);
    return (e - 1.f) / (e + 1.f);
}

__device__ __forceinline__ ushort_t f2bf(float f) {
    union { float f; unsigned int u; } x;
    x.f = f;
    unsigned int u = x.u;
    unsigned int r = (u + 0x7FFFu + ((u >> 16) & 1u)) >> 16;  // RNE
    return (ushort_t)r;
}

__device__ __forceinline__ uint4 pack8(float4 a, float4 b) {
    uint4 u;
    u.x = (unsigned)f2bf(a.x) | ((unsigned)f2bf(a.y) << 16);
    u.y = (unsigned)f2bf(a.z) | ((unsigned)f2bf(a.w) << 16);
    u.z = (unsigned)f2bf(b.x) | ((unsigned)f2bf(b.y) << 16);
    u.w = (unsigned)f2bf(b.z) | ((unsigned)f2bf(b.w) << 16);
    return u;
}

__device__ __forceinline__ unsigned pack_ea(float e, float a) {
    union { f16_t h[2]; unsigned u; } p;
    p.h[0] = (f16_t)e;
    p.h[1] = (f16_t)a;
    return p.u;
}

__device__ __forceinline__ f16x2 u2h2(unsigned u) {
    union { unsigned u; f16x2 h; } x;
    x.u = u;
    return x.h;
}

#if __has_builtin(__builtin_amdgcn_fdot2)
#define FDOT2(a, b, c) __builtin_amdgcn_fdot2((a), (b), (c), false)
#else
#define FDOT2(a, b, c) ((c) + (float)(a).x * (float)(b).x + (float)(a).y * (float)(b).y)
#endif

// ---------- workspace layout (float offsets) ----------
#define F_WQ   0u          // w       (B*L, 64) f16
#define F_EAQ  1638400u    // e,a packed half2  (B*L, 128) uint
#define F_FKQ  8192000u    // fk fragment-order f16
#define F_RD   11468800u   // reads   (B*L, 128) bf16
#define F_DIFF 14745600u   // que_diff (B*L) fp32
#define F_PACK 14771200u   // ushort region (16B aligned)
#define WPACK_N 59392      // 29 nts (28 = df_W in col 0)
#define FPACK_N 16384

struct KParams {
    const int* q;
    const int* r;
    const float* k_emb;
    const float* v_emb;
    const float* Mk;
    const float* Mv0;
    const float* f_W;
    const float* f_b;
    const float* e_W;
    const float* e_b;
    const float* a_W;
    const float* a_b;
    const float* ab_W;
    const float* ab_b;
    const float* df_W;
    const float* df_b;
    f16_t* wq;
    unsigned* eaq;
    f16_t* fkq;
    float* diffq;
    ushort_t* reads;
    ushort_t* Wpack;
    ushort_t* Fpack;
    float* out;
};

__device__ __forceinline__ void loadB4(const ushort_t* __restrict__ base,
                                       int nt, int lane, bf16x8* b) {
    const ushort_t* p = base + (nt * 256 + lane) * 8;
    b[0] = *(const bf16x8*)(p);
    b[1] = *(const bf16x8*)(p + 512);
    b[2] = *(const bf16x8*)(p + 1024);
    b[3] = *(const bf16x8*)(p + 1536);
}

// pbuf linear indexing: [2][8][8][64]
#define PBUF(bb, w, t, l) (((bb) * 4096) + ((w) * 512) + ((t) * 64) + (l))

#define SC_PREFETCH(wX, eX, cN)                                            \
    _Pragma("unroll")                                                      \
    for (int tt = 0; tt < 8; tt++) {                                       \
        wX[tt] = wh4[((cN) * 8 + tt) * 8 + sc];                            \
        eX[tt] = eab[((cN) * 8 + tt) * 128];                               \
    }

#define SC_COMPUTE(wX, eX, bb)                                             \
    _Pragma("unroll")                                                      \
    for (int tt = 0; tt < 8; tt++) {                                       \
        uint4 wp = wX[tt];                                                 \
        f16x2 w01 = u2h2(wp.x), w23 = u2h2(wp.y);                          \
        f16x2 w45 = u2h2(wp.z), w67 = u2h2(wp.w);                          \
        f16x2 ea = u2h2(eX[tt]);                                           \
        f16x2 ee = __builtin_shufflevector(ea, ea, 0, 0);                  \
        f16x2 av = __builtin_shufflevector(ea, ea, 1, 1);                  \
        float r0 = FDOT2(w01, Mv[0], 0.f);                                 \
        float r1 = FDOT2(w45, Mv[2], 0.f);                                 \
        r0 = FDOT2(w23, Mv[1], r0);                                        \
        r1 = FDOT2(w67, Mv[3], r1);                                        \
        Mv[0] = __builtin_elementwise_fma(w01,                             \
                    __builtin_elementwise_fma(-ee, Mv[0], av), Mv[0]);     \
        Mv[1] = __builtin_elementwise_fma(w23,                             \
                    __builtin_elementwise_fma(-ee, Mv[1], av), Mv[1]);     \
        Mv[2] = __builtin_elementwise_fma(w45,                             \
                    __builtin_elementwise_fma(-ee, Mv[2], av), Mv[2]);     \
        Mv[3] = __builtin_elementwise_fma(w67,                             \
                    __builtin_elementwise_fma(-ee, Mv[3], av), Mv[3]);     \
        pbuf[PBUF(bb, sc, tt, lane)] = r0 + r1;                            \
    }

#define SC_REDUCE(bb, c0) {                                                \
        float s = pbuf[PBUF(bb, 0, wv, lane)] + pbuf[PBUF(bb, 1, wv, lane)]\
                + pbuf[PBUF(bb, 2, wv, lane)] + pbuf[PBUF(bb, 3, wv, lane)]\
                + pbuf[PBUF(bb, 4, wv, lane)] + pbuf[PBUF(bb, 5, wv, lane)]\
                + pbuf[PBUF(bb, 6, wv, lane)] + pbuf[PBUF(bb, 7, wv, lane)];\
        rbase[((c0) * 8 + wv) * 128 + lane] = f2bf(s);                     \
    }

// ---------- fused kernel: pack -> projections -> scan -> final ----------
// 256 blocks x 512 threads (1 block/CU). __launch_bounds__(512,1): scan
// phase needs ~90-130 VGPRs live; round-2's (512,2) capped at 128 and the
// then-fp32 scan (160+ live) spilled ~1GB of scratch -> 300us. Fixed.
__global__ __launch_bounds__(512, 1) void k_fused(KParams P)
{
    __shared__ __align__(16) char smem[50688];

    const int tid = threadIdx.x;
    const int bid = blockIdx.x;
    const int wave = tid >> 6;
    const int lane = tid & 63;

    cg::grid_group grid = cg::this_grid();

    // ================= Phase A: weight pack =================
    {
        int i = bid * 512 + tid;
        if (i < WPACK_N) {
            int g = i >> 9, ln = (i >> 3) & 63, j = i & 7;
            int nt = g >> 2, ks = g & 3;
            int col = nt * 16 + (ln & 15);
            int d = ks * 32 + ((ln >> 4) << 3) + j;
            float v;
            if (col < 64)       v = P.Mk[col * 128 + d];
            else if (col < 192) v = P.e_W[(col - 64) * 128 + d];
            else if (col < 320) v = P.a_W[(col - 192) * 128 + d];
            else if (col < 448) v = P.f_W[(col - 320) * 256 + 128 + d];
            else                v = (col == 448) ? P.df_W[d] : 0.f;
            P.Wpack[i] = f2bf(v);
        } else if (i < WPACK_N + FPACK_N) {
            int e = i - WPACK_N;
            int g = e >> 9, ln = (e >> 3) & 63, j = e & 7;
            int nt = g >> 2, ks = g & 3;
            int col = nt * 16 + (ln & 15);
            int d = ks * 32 + ((ln >> 4) << 3) + j;
            P.Fpack[e] = f2bf(P.f_W[col * 256 + d]);
        }
    }
    __threadfence();
    grid.sync();

    // ================= Phase B: MFMA gather + projections + softmax + diff =================
    {
        ushort_t* skA = (ushort_t*)smem;          // 16 KB
        ushort_t* svA = skA + 8192;               // 16 KB
        float* slog = (float*)(smem + 32768);     // 17408 B

        const int* __restrict__ q = P.q;
        const int* __restrict__ r = P.r;
        const float* __restrict__ k_emb = P.k_emb;
        const float* __restrict__ v_emb = P.v_emb;
        const ushort_t* __restrict__ Wpack = P.Wpack;
        f16_t* __restrict__ wq = P.wq;
        unsigned* __restrict__ eaq = P.eaq;
        f16_t* __restrict__ fkq = P.fkq;
        float* __restrict__ diffq = P.diffq;

        const int mt = wave & 3;
        const int nh = wave >> 2;

        for (int t = bid; t < 400; t += 256) {
            const int pos0 = t * 64;

            #pragma unroll
            for (int i = 0; i < 2; i++) {
                int E = tid + 512 * i;
                int mtile = E >> 8, ks = (E >> 6) & 3, le = E & 63;
                int prow = pos0 + mtile * 16 + (le & 15);
                int dof = ks * 32 + ((le >> 4) << 3);
                int qv = q[prow], rv = r[prow];
                const float4* kp = (const float4*)(k_emb + qv * 128 + dof);
                float4 ka = kp[0], kb = kp[1];
                const float4* vp = (const float4*)(v_emb + rv * 128 + dof);
                float4 va = vp[0], vb = vp[1];
                *(uint4*)&skA[E * 8] = pack8(ka, kb);
                float4 s0, s1;
                s0.x = ka.x + va.x; s0.y = ka.y + va.y; s0.z = ka.z + va.z; s0.w = ka.w + va.w;
                s1.x = kb.x + vb.x; s1.y = kb.y + vb.y; s1.z = kb.z + vb.z; s1.w = kb.w + vb.w;
                *(uint4*)&svA[E * 8] = pack8(s0, s1);
            }
            __syncthreads();

            bf16x8 A[4];
            {
                const ushort_t* src = nh ? svA : skA;
                #pragma unroll
                for (int ks = 0; ks < 4; ks++)
                    A[ks] = *(const bf16x8*)&src[((mt * 4 + ks) * 64 + lane) * 8];
            }

            const int col = lane & 15;
            const int quad = lane >> 4;
            const int rbase = mt * 16 + quad * 4;

            if (nh == 0) {
                bf16x8 Bb[2][4];
                loadB4(Wpack, 0, lane, Bb[0]);
                #pragma unroll
                for (int j = 0; j < 13; j++) {
                    if (j < 12) {
                        int jn = j + 1;
                        loadB4(Wpack, (jn < 4) ? jn : jn + 16, lane, Bb[jn & 1]);
                    }
                    f32x4 acc = {0.f, 0.f, 0.f, 0.f};
                    #pragma unroll
                    for (int ks = 0; ks < 4; ks++)
                        acc = __builtin_amdgcn_mfma_f32_16x16x32_bf16(A[ks], Bb[j & 1][ks], acc, 0, 0, 0);
                    if (j < 4) {
                        #pragma unroll
                        for (int reg = 0; reg < 4; reg++)
                            slog[(rbase + reg) * 68 + j * 16 + col] = acc[reg];
                    } else if (j < 12) {
                        int base = (((t * 4 + mt) * 8 + (j - 4)) * 4) * 64;
                        #pragma unroll
                        for (int reg = 0; reg < 4; reg++)
                            fkq[base + reg * 64 + lane] = (f16_t)acc[reg];
                    } else {
                        if (col == 0) {
                            float db = P.df_b[0];
                            #pragma unroll
                            for (int reg = 0; reg < 4; reg++)
                                diffq[pos0 + rbase + reg] = fast_tanh(acc[reg] + db);
                        }
                    }
                }
                // softmax (threads 0-255, 4 per row)
                {
                    int row = tid >> 2, ln = tid & 3;
                    const float* lr = slog + row * 68 + ln * 16;
                    float v[16];
                    #pragma unroll
                    for (int j = 0; j < 16; j++) v[j] = lr[j];
                    float mx = v[0];
                    #pragma unroll
                    for (int j = 1; j < 16; j++) mx = fmaxf(mx, v[j]);
                    mx = fmaxf(mx, __shfl_xor(mx, 1));
                    mx = fmaxf(mx, __shfl_xor(mx, 2));
                    float s = 0.f;
                    #pragma unroll
                    for (int j = 0; j < 16; j++) { v[j] = __expf(v[j] - mx); s += v[j]; }
                    s += __shfl_xor(s, 1); s += __shfl_xor(s, 2);
                    float inv = 1.f / s;
                    union { f16_t h[8]; uint4 u; } o0, o1;
                    #pragma unroll
                    for (int j = 0; j < 8; j++) o0.h[j] = (f16_t)(v[j] * inv);
                    #pragma unroll
                    for (int j = 0; j < 8; j++) o1.h[j] = (f16_t)(v[8 + j] * inv);
                    f16_t* wout = wq + (pos0 + row) * 64 + ln * 16;
                    *(uint4*)(wout) = o0.u;
                    *(uint4*)(wout + 8) = o1.u;
                }
            } else {
                bf16x8 Be[2][4], Ba[2][4];
                loadB4(Wpack, 4, lane, Be[0]);
                loadB4(Wpack, 12, lane, Ba[0]);
                #pragma unroll
                for (int i = 0; i < 8; i++) {
                    if (i < 7) {
                        loadB4(Wpack, 5 + i, lane, Be[(i + 1) & 1]);
                        loadB4(Wpack, 13 + i, lane, Ba[(i + 1) & 1]);
                    }
                    f32x4 ae = {0.f, 0.f, 0.f, 0.f};
                    f32x4 aa = {0.f, 0.f, 0.f, 0.f};
                    #pragma unroll
                    for (int ks = 0; ks < 4; ks++) {
                        ae = __builtin_amdgcn_mfma_f32_16x16x32_bf16(A[ks], Be[i & 1][ks], ae, 0, 0, 0);
                        aa = __builtin_amdgcn_mfma_f32_16x16x32_bf16(A[ks], Ba[i & 1][ks], aa, 0, 0, 0);
                    }
                    int c = i * 16 + col;
                    float ebv = P.e_b[c], abv = P.a_b[c];
                    #pragma unroll
                    for (int reg = 0; reg < 4; reg++) {
                        float ev = fast_sigmoid(ae[reg] + ebv);
                        float av = fast_tanh(aa[reg] + abv);
                        eaq[(pos0 + rbase + reg) * 128 + c] = pack_ea(ev, av);
                    }
                }
            }
            __syncthreads();   // protect LDS reuse across tile iterations
        }
    }
    __threadfence();
    grid.sync();

    // ================= Phase C: scan (packed-f16 state) =================
    {
        float* pbuf = (float*)smem;   // [2][8][8][64] = 32 KB

        const f16_t* __restrict__ wq = P.wq;
        const unsigned* __restrict__ eaq = P.eaq;
        const float* __restrict__ Mv0 = P.Mv0;
        ushort_t* __restrict__ reads = P.reads;

        const int b = bid >> 1;
        const int dh = bid & 1;
        const int wv = wave;
        const int sc = __builtin_amdgcn_readfirstlane(wv);
        const int d = dh * 64 + lane;

        f16x2 Mv[4];
        #pragma unroll
        for (int j = 0; j < 4; j++) {
            f16x2 m;
            m.x = (f16_t)Mv0[(sc * 8 + 2 * j) * D_ + d];
            m.y = (f16_t)Mv0[(sc * 8 + 2 * j + 1) * D_ + d];
            Mv[j] = m;
        }

        const uint4* wh4 = (const uint4*)(wq + b * (L_ * M_));
        const unsigned* eab = eaq + b * (L_ * 128) + d;
        ushort_t* rbase = reads + b * (L_ * D_) + dh * 64;

        uint4 wA[8], wB[8];
        unsigned eA[8], eB[8];

        SC_PREFETCH(wA, eA, 0);

        for (int cc = 0; cc < 12; cc++) {
            const int c0 = 2 * cc;
            SC_PREFETCH(wB, eB, c0 + 1);
            SC_COMPUTE(wA, eA, 0);
            __syncthreads();
            SC_REDUCE(0, c0);
            SC_PREFETCH(wA, eA, c0 + 2);
            SC_COMPUTE(wB, eB, 1);
            __syncthreads();
            SC_REDUCE(1, c0 + 1);
        }
        SC_COMPUTE(wA, eA, 0);
        __syncthreads();
        SC_REDUCE(0, 24);
    }
    __threadfence();
    grid.sync();

    // ================= Phase D: final MFMA + epilogue =================
    // reads is bf16 row-major: A-fragments are direct contiguous 16B loads
    // (no LDS staging needed -- that was only for phase B's gather dedup).
    {
        float* sab = (float*)smem;    // 512 B

        const ushort_t* __restrict__ reads = P.reads;
        const f16_t* __restrict__ fkq = P.fkq;
        const float* __restrict__ diffq = P.diffq;
        const ushort_t* __restrict__ Fpack = P.Fpack;
        float* __restrict__ out = P.out;

        const int mt = wave & 3;
        const int half = wave >> 2;
        const int col = lane & 15;
        const int quad = lane >> 4;
        const int rbase = mt * 16 + quad * 4;

        for (int t = bid; t < 400; t += 256) {
            const int pos0 = t * 64;

            // direct A-frag loads: 4 x 16B per thread
            bf16x8 A[4];
            {
                const ushort_t* arow = reads
                    + (pos0 + mt * 16 + (lane & 15)) * 128 + ((lane >> 4) << 3);
                #pragma unroll
                for (int ks = 0; ks < 4; ks++)
                    A[ks] = *(const bf16x8*)(arow + ks * 32);
            }

            // fragment-order fkq prefetch: coalesced 128B per (jj,reg)
            float fkv[16];
            #pragma unroll
            for (int i = 0; i < 4; i++) {
                int base = (((t * 4 + mt) * 8 + (half * 4 + i)) * 4) * 64;
                #pragma unroll
                for (int reg = 0; reg < 4; reg++)
                    fkv[i * 4 + reg] = (float)fkq[base + reg * 64 + lane];
            }

            float abacc[4] = {0.f, 0.f, 0.f, 0.f};

            bf16x8 Bb[2][4];
            loadB4(Fpack, half * 4, lane, Bb[0]);
            #pragma unroll
            for (int i = 0; i < 4; i++) {
                if (i < 3) loadB4(Fpack, half * 4 + i + 1, lane, Bb[(i + 1) & 1]);
                f32x4 acc = {0.f, 0.f, 0.f, 0.f};
                #pragma unroll
                for (int ks = 0; ks < 4; ks++)
                    acc = __builtin_amdgcn_mfma_f32_16x16x32_bf16(A[ks], Bb[i & 1][ks], acc, 0, 0, 0);
                int c = (half * 4 + i) * 16 + col;
                float fb = P.f_b[c];
                float abw = P.ab_W[c];
                #pragma unroll
                for (int reg = 0; reg < 4; reg++) {
                    float fv = fast_tanh(acc[reg] + fkv[i * 4 + reg] + fb);
                    abacc[reg] = fmaf(abw, fv, abacc[reg]);
                }
            }

            #pragma unroll
            for (int reg = 0; reg < 4; reg++) {
                float v = abacc[reg];
                v += __shfl_xor(v, 1); v += __shfl_xor(v, 2);
                v += __shfl_xor(v, 4); v += __shfl_xor(v, 8);
                abacc[reg] = v;
            }
            if (col == 0) {
                #pragma unroll
                for (int reg = 0; reg < 4; reg++)
                    sab[(rbase + reg) * 2 + half] = abacc[reg];
            }
            __syncthreads();
            if (tid < 64) {
                float ab = fast_tanh(sab[tid * 2] + sab[tid * 2 + 1] + P.ab_b[0]);
                int pos = pos0 + tid;
                out[pos] = fast_sigmoid(3.f * ab - diffq[pos]);
            }
            __syncthreads();   // protect sab reuse across tile iterations
        }
    }
}

// ---------- launch ----------
extern "C" void kernel_launch(void* const* d_in, const int* in_sizes, int n_in,
                              void* d_out, int out_size, void* d_ws, size_t ws_size,
                              hipStream_t stream)
{
    float* ws = (float*)d_ws;
    ushort_t* Wpack = (ushort_t*)(ws + F_PACK);

    KParams P;
    P.q     = (const int*)d_in[0];
    P.r     = (const int*)d_in[1];
    P.k_emb = (const float*)d_in[2];
    P.v_emb = (const float*)d_in[3];
    P.Mk    = (const float*)d_in[4];
    P.Mv0   = (const float*)d_in[5];
    P.f_W   = (const float*)d_in[6];
    P.f_b   = (const float*)d_in[7];
    P.e_W   = (const float*)d_in[8];
    P.e_b   = (const float*)d_in[9];
    P.a_W   = (const float*)d_in[10];
    P.a_b   = (const float*)d_in[11];
    P.ab_W  = (const float*)d_in[12];
    P.ab_b  = (const float*)d_in[13];
    P.df_W  = (const float*)d_in[14];
    P.df_b  = (const float*)d_in[15];
    P.wq    = (f16_t*)(ws + F_WQ);
    P.eaq   = (unsigned*)(ws + F_EAQ);
    P.fkq   = (f16_t*)(ws + F_FKQ);
    P.diffq = ws + F_DIFF;
    P.reads = (ushort_t*)(ws + F_RD);
    P.Wpack = Wpack;
    P.Fpack = Wpack + WPACK_N;
    P.out   = (float*)d_out;

    void* args[] = { &P };
    hipLaunchCooperativeKernel((const void*)k_fused, dim3(256), dim3(512),
                               args, 0, stream);
}

// Round 6
// 137.383 us; speedup vs baseline: 2.8904x; 2.8904x over previous
//
#include <hip/hip_runtime.h>

typedef unsigned short ushort_t;
typedef _Float16 f16_t;
typedef _Float16 f16x2 __attribute__((ext_vector_type(2)));
typedef short bf16x8 __attribute__((ext_vector_type(8)));
typedef float f32x4 __attribute__((ext_vector_type(4)));

#define B_ 128
#define L_ 200
#define D_ 128
#define M_ 64

// ---------- helpers ----------
__device__ __forceinline__ float fast_sigmoid(float x) {
    return 1.f / (1.f + __expf(-x));
}

__device__ __forceinline__ float fast_tanh(float x) {
    float xc = fminf(fmaxf(x, -15.f), 15.f);
    float e = __expf(2.f * xc);
    return (e - 1.f) / (e + 1.f);
}

__device__ __forceinline__ ushort_t f2bf(float f) {
    union { float f; unsigned int u; } x;
    x.f = f;
    unsigned int u = x.u;
    unsigned int r = (u + 0x7FFFu + ((u >> 16) & 1u)) >> 16;  // RNE
    return (ushort_t)r;
}

__device__ __forceinline__ uint4 pack8(float4 a, float4 b) {
    uint4 u;
    u.x = (unsigned)f2bf(a.x) | ((unsigned)f2bf(a.y) << 16);
    u.y = (unsigned)f2bf(a.z) | ((unsigned)f2bf(a.w) << 16);
    u.z = (unsigned)f2bf(b.x) | ((unsigned)f2bf(b.y) << 16);
    u.w = (unsigned)f2bf(b.z) | ((unsigned)f2bf(b.w) << 16);
    return u;
}

__device__ __forceinline__ unsigned pack_ea(float e, float a) {
    union { f16_t h[2]; unsigned u; } p;
    p.h[0] = (f16_t)e;
    p.h[1] = (f16_t)a;
    return p.u;
}

__device__ __forceinline__ f16x2 u2h2(unsigned u) {
    union { unsigned u; f16x2 h; } x;
    x.u = u;
    return x.h;
}

#if __has_builtin(__builtin_amdgcn_fdot2)
#define FDOT2(a, b, c) __builtin_amdgcn_fdot2((a), (b), (c), false)
#else
#define FDOT2(a, b, c) ((c) + (float)(a).x * (float)(b).x + (float)(a).y * (float)(b).y)
#endif

// ---------- workspace layout (float offsets) ----------
#define F_WQ   0u          // w       (B*L, 64) f16
#define F_EAQ  1638400u    // e,a packed half2  (B*L, 128) uint
#define F_FKQ  8192000u    // fk fragment-order f16: [(tile*4+mt)*8+jj][reg(4)][lane(64)]
#define F_RD   11468800u   // reads   (B*L, 128) bf16
#define F_DIFF 14745600u   // que_diff (B*L) fp32
#define F_PACK 14771200u   // ushort region starts here (16B aligned)
#define WPACK_N 59392      // 29 nts (28 = df_W in col 0)
#define FPACK_N 16384

// ---------- K0: pack weights into bf16 MFMA-B fragment order ----------
// nt 0-3: Mk; nt 4-11: e_W; nt 12-19: a_W; nt 20-27: f_W right half (k);
// nt 28: col 0 = df_W, cols 1-15 = 0.
__global__ __launch_bounds__(256) void k_pack(
    const float* __restrict__ Mk, const float* __restrict__ eW,
    const float* __restrict__ aW, const float* __restrict__ fW,
    const float* __restrict__ dfW,
    ushort_t* __restrict__ Wpack, ushort_t* __restrict__ Fpack)
{
    int i = blockIdx.x * 256 + threadIdx.x;
    if (i < WPACK_N) {
        int g = i >> 9, lane = (i >> 3) & 63, j = i & 7;
        int nt = g >> 2, ks = g & 3;
        int col = nt * 16 + (lane & 15);
        int d = ks * 32 + ((lane >> 4) << 3) + j;
        float v;
        if (col < 64)       v = Mk[col * 128 + d];
        else if (col < 192) v = eW[(col - 64) * 128 + d];
        else if (col < 320) v = aW[(col - 192) * 128 + d];
        else if (col < 448) v = fW[(col - 320) * 256 + 128 + d];  // right half: k
        else                v = (col == 448) ? dfW[d] : 0.f;      // nt 28: df_W
        Wpack[i] = f2bf(v);
    } else if (i < WPACK_N + FPACK_N) {
        int e = i - WPACK_N;
        int g = e >> 9, lane = (e >> 3) & 63, j = e & 7;
        int nt = g >> 2, ks = g & 3;
        int col = nt * 16 + (lane & 15);
        int d = ks * 32 + ((lane >> 4) << 3) + j;
        Fpack[e] = f2bf(fW[col * 256 + d]);  // left half: reads
    }
}

__device__ __forceinline__ void loadB4(const ushort_t* __restrict__ base,
                                       int nt, int lane, bf16x8* b) {
    const ushort_t* p = base + (nt * 256 + lane) * 8;
    b[0] = *(const bf16x8*)(p);
    b[1] = *(const bf16x8*)(p + 512);
    b[2] = *(const bf16x8*)(p + 1024);
    b[3] = *(const bf16x8*)(p + 1536);
}

// ---------- K1: unified MFMA gather+projections+softmax+diff ----------
// 400 blocks x 512 thr. One gather per 64-pos group (k and v both staged).
// waves 0-3 (nh=0): logits nt0-3 + fk nt20-27 + diff nt28 (A=k), then softmax
// waves 4-7 (nh=1): e nt4-11 paired with a nt12-19 (A=v)
__global__ __launch_bounds__(512) void k_pre_mfma(
    const int* __restrict__ q, const int* __restrict__ r,
    const float* __restrict__ k_emb, const float* __restrict__ v_emb,
    const ushort_t* __restrict__ Wpack,
    const float* __restrict__ e_b, const float* __restrict__ a_b,
    const float* __restrict__ df_b,
    f16_t* __restrict__ wq, unsigned* __restrict__ eaq,
    f16_t* __restrict__ fkq, float* __restrict__ diffq)
{
    __shared__ ushort_t skA[8192];
    __shared__ ushort_t svA[8192];
    __shared__ float slog[64 * 68];

    const int tid = threadIdx.x;
    const int pos0 = blockIdx.x * 64;
    const int wave = tid >> 6;
    const int lane = tid & 63;
    const int mt = wave & 3;
    const int nh = wave >> 2;

    // --- single gather: stage k and v A-frags (bf16) ---
    #pragma unroll
    for (int i = 0; i < 2; i++) {
        int E = tid + 512 * i;              // 1024 entries, 8 elems each
        int mtile = E >> 8, ks = (E >> 6) & 3, le = E & 63;
        int prow = pos0 + mtile * 16 + (le & 15);
        int dof = ks * 32 + ((le >> 4) << 3);
        int qv = q[prow], rv = r[prow];
        const float4* kp = (const float4*)(k_emb + qv * 128 + dof);
        float4 ka = kp[0], kb = kp[1];
        const float4* vp = (const float4*)(v_emb + rv * 128 + dof);
        float4 va = vp[0], vb = vp[1];
        *(uint4*)&skA[E * 8] = pack8(ka, kb);
        float4 s0, s1;
        s0.x = ka.x + va.x; s0.y = ka.y + va.y; s0.z = ka.z + va.z; s0.w = ka.w + va.w;
        s1.x = kb.x + vb.x; s1.y = kb.y + vb.y; s1.z = kb.z + vb.z; s1.w = kb.w + vb.w;
        *(uint4*)&svA[E * 8] = pack8(s0, s1);
    }
    __syncthreads();

    bf16x8 A[4];
    {
        const ushort_t* src = nh ? svA : skA;
        #pragma unroll
        for (int ks = 0; ks < 4; ks++)
            A[ks] = *(const bf16x8*)&src[((mt * 4 + ks) * 64 + lane) * 8];
    }

    const int col = lane & 15;
    const int quad = lane >> 4;
    const int rbase = mt * 16 + quad * 4;

    if (nh == 0) {
        // 13 nts: j 0-3 -> nt j (logits->slog), j 4-11 -> nt j+16 (fk, fragment
        // layout), j 12 -> nt 28 (diff, col 0)
        bf16x8 Bb[2][4];
        loadB4(Wpack, 0, lane, Bb[0]);
        #pragma unroll
        for (int j = 0; j < 13; j++) {
            if (j < 12) {
                int jn = j + 1;
                loadB4(Wpack, (jn < 4) ? jn : jn + 16, lane, Bb[jn & 1]);
            }
            f32x4 acc = {0.f, 0.f, 0.f, 0.f};
            #pragma unroll
            for (int ks = 0; ks < 4; ks++)
                acc = __builtin_amdgcn_mfma_f32_16x16x32_bf16(A[ks], Bb[j & 1][ks], acc, 0, 0, 0);
            if (j < 4) {
                #pragma unroll
                for (int reg = 0; reg < 4; reg++)
                    slog[(rbase + reg) * 68 + j * 16 + col] = acc[reg];
            } else if (j < 12) {
                // fragment-order store: lane-contiguous 128B per reg
                int base = (((blockIdx.x * 4 + mt) * 8 + (j - 4)) * 4) * 64;
                #pragma unroll
                for (int reg = 0; reg < 4; reg++)
                    fkq[base + reg * 64 + lane] = (f16_t)acc[reg];
            } else {
                // diff: col 0 of nt 28 holds dot(k_row, df_W)
                if (col == 0) {
                    float db = df_b[0];
                    #pragma unroll
                    for (int reg = 0; reg < 4; reg++)
                        diffq[pos0 + rbase + reg] = fast_tanh(acc[reg] + db);
                }
            }
        }
        // softmax over slog rows (waves 0-3 = threads 0-255, 4 per row)
        {
            int row = tid >> 2, ln = tid & 3;
            const float* lr = slog + row * 68 + ln * 16;
            float v[16];
            #pragma unroll
            for (int j = 0; j < 16; j++) v[j] = lr[j];
            float mx = v[0];
            #pragma unroll
            for (int j = 1; j < 16; j++) mx = fmaxf(mx, v[j]);
            mx = fmaxf(mx, __shfl_xor(mx, 1));
            mx = fmaxf(mx, __shfl_xor(mx, 2));
            float s = 0.f;
            #pragma unroll
            for (int j = 0; j < 16; j++) { v[j] = __expf(v[j] - mx); s += v[j]; }
            s += __shfl_xor(s, 1); s += __shfl_xor(s, 2);
            float inv = 1.f / s;
            // f16 store: 16 halves = 2 x uint4
            union { f16_t h[8]; uint4 u; } o0, o1;
            #pragma unroll
            for (int j = 0; j < 8; j++) o0.h[j] = (f16_t)(v[j] * inv);
            #pragma unroll
            for (int j = 0; j < 8; j++) o1.h[j] = (f16_t)(v[8 + j] * inv);
            f16_t* wout = wq + (pos0 + row) * 64 + ln * 16;
            *(uint4*)(wout) = o0.u;
            *(uint4*)(wout + 8) = o1.u;
        }
    } else {
        // 8 paired nts: e = nt 4+i, a = nt 12+i; fused half2 store
        bf16x8 Be[2][4], Ba[2][4];
        loadB4(Wpack, 4, lane, Be[0]);
        loadB4(Wpack, 12, lane, Ba[0]);
        #pragma unroll
        for (int i = 0; i < 8; i++) {
            if (i < 7) {
                loadB4(Wpack, 5 + i, lane, Be[(i + 1) & 1]);
                loadB4(Wpack, 13 + i, lane, Ba[(i + 1) & 1]);
            }
            f32x4 ae = {0.f, 0.f, 0.f, 0.f};
            f32x4 aa = {0.f, 0.f, 0.f, 0.f};
            #pragma unroll
            for (int ks = 0; ks < 4; ks++) {
                ae = __builtin_amdgcn_mfma_f32_16x16x32_bf16(A[ks], Be[i & 1][ks], ae, 0, 0, 0);
                aa = __builtin_amdgcn_mfma_f32_16x16x32_bf16(A[ks], Ba[i & 1][ks], aa, 0, 0, 0);
            }
            int c = i * 16 + col;
            float ebv = e_b[c], abv = a_b[c];
            #pragma unroll
            for (int reg = 0; reg < 4; reg++) {
                float ev = fast_sigmoid(ae[reg] + ebv);
                float av = fast_tanh(aa[reg] + abv);
                eaq[(pos0 + rbase + reg) * 128 + c] = pack_ea(ev, av);
            }
        }
    }
}

// ---------- K2: scan — packed-f16 state, 8 waves (8 m x 64 d) ----------
// Mv state: f16x2 pairs (2 m per VGPR). Update via v_pk_fma_f16 (2 ops/pair),
// read via v_dot2_f32_f16 (fp32 accumulate). w stored f16 by K1 (uniform
// 16B load per tt per wave). e,a consumed directly as the packed f16 pair.
#define SC_PREFETCH(wX, eX, cN)                                            \
    _Pragma("unroll")                                                      \
    for (int tt = 0; tt < 8; tt++) {                                       \
        wX[tt] = wh4[((cN) * 8 + tt) * 8 + sc];                            \
        eX[tt] = eab[((cN) * 8 + tt) * 128];                               \
    }

#define SC_COMPUTE(wX, eX, bb)                                             \
    _Pragma("unroll")                                                      \
    for (int tt = 0; tt < 8; tt++) {                                       \
        uint4 wp = wX[tt];                                                 \
        f16x2 w01 = u2h2(wp.x), w23 = u2h2(wp.y);                          \
        f16x2 w45 = u2h2(wp.z), w67 = u2h2(wp.w);                          \
        f16x2 ea = u2h2(eX[tt]);                                           \
        f16x2 ee = __builtin_shufflevector(ea, ea, 0, 0);                  \
        f16x2 av = __builtin_shufflevector(ea, ea, 1, 1);                  \
        float r0 = FDOT2(w01, Mv[0], 0.f);                                 \
        float r1 = FDOT2(w45, Mv[2], 0.f);                                 \
        r0 = FDOT2(w23, Mv[1], r0);                                        \
        r1 = FDOT2(w67, Mv[3], r1);                                        \
        Mv[0] = __builtin_elementwise_fma(w01,                             \
                    __builtin_elementwise_fma(-ee, Mv[0], av), Mv[0]);     \
        Mv[1] = __builtin_elementwise_fma(w23,                             \
                    __builtin_elementwise_fma(-ee, Mv[1], av), Mv[1]);     \
        Mv[2] = __builtin_elementwise_fma(w45,                             \
                    __builtin_elementwise_fma(-ee, Mv[2], av), Mv[2]);     \
        Mv[3] = __builtin_elementwise_fma(w67,                             \
                    __builtin_elementwise_fma(-ee, Mv[3], av), Mv[3]);     \
        pbuf[bb][sc][tt][lane] = r0 + r1;                                  \
    }

#define SC_REDUCE(bb, c0) {                                                \
        float s = pbuf[bb][0][wv][lane] + pbuf[bb][1][wv][lane]            \
                + pbuf[bb][2][wv][lane] + pbuf[bb][3][wv][lane]            \
                + pbuf[bb][4][wv][lane] + pbuf[bb][5][wv][lane]            \
                + pbuf[bb][6][wv][lane] + pbuf[bb][7][wv][lane];           \
        rbase[((c0) * 8 + wv) * 128 + lane] = f2bf(s);                     \
    }

__global__ __launch_bounds__(512, 2) void k_scan(
    const f16_t* __restrict__ wq, const unsigned* __restrict__ eaq,
    const float* __restrict__ Mv0, ushort_t* __restrict__ reads)
{
    __shared__ float pbuf[2][8][8][64];   // 32 KB

    const int tid = threadIdx.x;
    const int b = blockIdx.x >> 1;
    const int dh = blockIdx.x & 1;
    const int wv = tid >> 6;                                   // 0..7
    const int sc = __builtin_amdgcn_readfirstlane(wv);         // uniform wave id
    const int lane = tid & 63;
    const int d = dh * 64 + lane;

    f16x2 Mv[4];
    #pragma unroll
    for (int j = 0; j < 4; j++) {
        f16x2 m;
        m.x = (f16_t)Mv0[(sc * 8 + 2 * j) * D_ + d];
        m.y = (f16_t)Mv0[(sc * 8 + 2 * j + 1) * D_ + d];
        Mv[j] = m;
    }

    const uint4* wh4 = (const uint4*)(wq + b * (L_ * M_));
    const unsigned* eab = eaq + b * (L_ * 128) + d;
    ushort_t* rbase = reads + b * (L_ * D_) + dh * 64;

    uint4 wA[8], wB[8];
    unsigned eA[8], eB[8];

    SC_PREFETCH(wA, eA, 0);

    for (int cc = 0; cc < 12; cc++) {
        const int c0 = 2 * cc;
        SC_PREFETCH(wB, eB, c0 + 1);
        SC_COMPUTE(wA, eA, 0);
        __syncthreads();
        SC_REDUCE(0, c0);
        SC_PREFETCH(wA, eA, c0 + 2);
        SC_COMPUTE(wB, eB, 1);
        __syncthreads();
        SC_REDUCE(1, c0 + 1);
    }
    SC_COMPUTE(wA, eA, 0);
    __syncthreads();
    SC_REDUCE(0, 24);
}

// ---------- K3: MFMA f-GEMM + fused ab/out epilogue (8 waves) ----------
// reads bf16 row-major -> A-fragments are DIRECT contiguous 16B global loads
// (LDS staging removed; the stage was a vestige of K1's gather dedup).
// fkq read in matching fragment order (coalesced).
__global__ __launch_bounds__(512) void k_final_mfma(
    const ushort_t* __restrict__ reads, const f16_t* __restrict__ fkq,
    const float* __restrict__ diffq, const ushort_t* __restrict__ Fpack,
    const float* __restrict__ f_b, const float* __restrict__ ab_W,
    const float* __restrict__ ab_b, float* __restrict__ out)
{
    __shared__ float sab[64 * 2];

    const int tid = threadIdx.x;
    const int pos0 = blockIdx.x * 64;
    const int wave = tid >> 6;
    const int lane = tid & 63;
    const int mt = wave & 3;        // m-tile
    const int half = wave >> 2;     // nt half

    const int col = lane & 15;
    const int quad = lane >> 4;
    const int rbase = mt * 16 + quad * 4;

    // direct A-frag loads: 4 x 16B contiguous per thread
    bf16x8 A[4];
    {
        const ushort_t* arow = reads
            + (pos0 + mt * 16 + (lane & 15)) * 128 + ((lane >> 4) << 3);
        #pragma unroll
        for (int ks = 0; ks < 4; ks++)
            A[ks] = *(const bf16x8*)(arow + ks * 32);
    }

    // fragment-order fkq prefetch: coalesced 128B per (jj,reg)
    float fkv[16];
    #pragma unroll
    for (int i = 0; i < 4; i++) {
        int base = (((blockIdx.x * 4 + mt) * 8 + (half * 4 + i)) * 4) * 64;
        #pragma unroll
        for (int reg = 0; reg < 4; reg++)
            fkv[i * 4 + reg] = (float)fkq[base + reg * 64 + lane];
    }

    float abacc[4] = {0.f, 0.f, 0.f, 0.f};

    bf16x8 Bb[2][4];
    loadB4(Fpack, half * 4, lane, Bb[0]);
    #pragma unroll
    for (int i = 0; i < 4; i++) {
        if (i < 3) loadB4(Fpack, half * 4 + i + 1, lane, Bb[(i + 1) & 1]);
        f32x4 acc = {0.f, 0.f, 0.f, 0.f};
        #pragma unroll
        for (int ks = 0; ks < 4; ks++)
            acc = __builtin_amdgcn_mfma_f32_16x16x32_bf16(A[ks], Bb[i & 1][ks], acc, 0, 0, 0);
        int c = (half * 4 + i) * 16 + col;
        float fb = f_b[c];
        float abw = ab_W[c];
        #pragma unroll
        for (int reg = 0; reg < 4; reg++) {
            float fv = fast_tanh(acc[reg] + fkv[i * 4 + reg] + fb);
            abacc[reg] = fmaf(abw, fv, abacc[reg]);
        }
    }

    #pragma unroll
    for (int reg = 0; reg < 4; reg++) {
        float v = abacc[reg];
        v += __shfl_xor(v, 1); v += __shfl_xor(v, 2);
        v += __shfl_xor(v, 4); v += __shfl_xor(v, 8);
        abacc[reg] = v;
    }
    if (col == 0) {
        #pragma unroll
        for (int reg = 0; reg < 4; reg++)
            sab[(rbase + reg) * 2 + half] = abacc[reg];
    }
    __syncthreads();
    if (tid < 64) {
        float ab = fast_tanh(sab[tid * 2] + sab[tid * 2 + 1] + ab_b[0]);
        int pos = pos0 + tid;
        out[pos] = fast_sigmoid(3.f * ab - diffq[pos]);
    }
}

// ---------- launch ----------
extern "C" void kernel_launch(void* const* d_in, const int* in_sizes, int n_in,
                              void* d_out, int out_size, void* d_ws, size_t ws_size,
                              hipStream_t stream)
{
    const int*   q     = (const int*)d_in[0];
    const int*   r     = (const int*)d_in[1];
    const float* k_emb = (const float*)d_in[2];
    const float* v_emb = (const float*)d_in[3];
    const float* Mk    = (const float*)d_in[4];
    const float* Mv0   = (const float*)d_in[5];
    const float* f_W   = (const float*)d_in[6];
    const float* f_b   = (const float*)d_in[7];
    const float* e_W   = (const float*)d_in[8];
    const float* e_b   = (const float*)d_in[9];
    const float* a_W   = (const float*)d_in[10];
    const float* a_b   = (const float*)d_in[11];
    const float* ab_W  = (const float*)d_in[12];
    const float* ab_b  = (const float*)d_in[13];
    const float* df_W  = (const float*)d_in[14];
    const float* df_b  = (const float*)d_in[15];

    float* ws = (float*)d_ws;
    float* out = (float*)d_out;
    f16_t*    wq_h    = (f16_t*)(ws + F_WQ);
    unsigned* eaq_u   = (unsigned*)(ws + F_EAQ);
    f16_t*    fkq_h   = (f16_t*)(ws + F_FKQ);
    ushort_t* reads_b = (ushort_t*)(ws + F_RD);
    ushort_t* Wpack = (ushort_t*)(ws + F_PACK);
    ushort_t* Fpack = Wpack + WPACK_N;

    // K0: pack weights to bf16 fragment layout (incl. df_W as nt 28)
    k_pack<<<296, 256, 0, stream>>>(Mk, e_W, a_W, f_W, df_W, Wpack, Fpack);

    // K1: unified MFMA projections + softmax + diff (400 blocks x 8 waves)
    k_pre_mfma<<<400, 512, 0, stream>>>(
        q, r, k_emb, v_emb, Wpack, e_b, a_b, df_b,
        wq_h, eaq_u, fkq_h, ws + F_DIFF);

    // K2: scan (128 b x 2 d-halves, 8 waves, packed-f16 state)
    k_scan<<<256, 512, 0, stream>>>(
        wq_h, eaq_u, Mv0, reads_b);

    // K3: final MFMA + epilogue (400 blocks x 8 waves, direct A loads)
    k_final_mfma<<<400, 512, 0, stream>>>(
        reads_b, fkq_h, ws + F_DIFF, Fpack,
        f_b, ab_W, ab_b, out);
}